// Round 7
// baseline (411.642 us; speedup 1.0000x reference)
//
#include <hip/hip_runtime.h>
#include <hip/hip_bf16.h>
#include <math.h>

#define D 128
#define DD (128 * 128)
#define BCAP 6400   // per-dst-bucket LDS edge capacity (avg 4096, sigma ~64)

typedef __attribute__((ext_vector_type(8))) short short8;
typedef __attribute__((ext_vector_type(4))) float f32x4;

__device__ __forceinline__ float bf2f(unsigned short u) {
    union { unsigned int i; float f; } x; x.i = ((unsigned int)u) << 16; return x.f;
}
__device__ __forceinline__ unsigned short f2bf(float f) {
    unsigned int i = __float_as_uint(f);
    unsigned int r = (i + 0x7FFFu + ((i >> 16) & 1u)) >> 16;  // RNE
    return (unsigned short)r;
}

// inline dtype vote: fp32 read as shorts -> ~50% random exponent fields. 256-thread blocks.
__device__ __forceinline__ int vote_flag(const unsigned short* __restrict__ x) {
    __shared__ int bad_s;
    if (threadIdx.x == 0) bad_s = 0;
    __syncthreads();
    unsigned int e = (x[threadIdx.x] >> 7) & 0xFFu;
    unsigned long long b = __ballot(e < 100u || e > 140u);
    if ((threadIdx.x & 63) == 0) atomicAdd(&bad_s, __popcll(b));
    __syncthreads();
    return bad_s > 48 ? 1 : 0;
}

// ---------------- normalize x (vec4) + all 9 weight tensors, one kernel ----------------
__global__ __launch_bounds__(256) void k_normall(
    const void* __restrict__ xin, unsigned short* __restrict__ xb, int n4, int nbx,
    const void* s0, const void* s1, const void* s2, const void* s3,
    const void* s4, const void* s5, const void* s6, const void* s7, const void* s8,
    int o1, int o2, int o3, int o4, int o5, int o6, int o7, int o8,
    int total, unsigned short* __restrict__ wdst)
{
    int fl = vote_flag((const unsigned short*)xin);
    if (blockIdx.x < nbx) {
        int i = blockIdx.x * 256 + threadIdx.x;
        if (i >= n4) return;
        if (fl) {
            float4 v = ((const float4*)xin)[i];
            uint2 o;
            o.x = (unsigned int)f2bf(v.x) | ((unsigned int)f2bf(v.y) << 16);
            o.y = (unsigned int)f2bf(v.z) | ((unsigned int)f2bf(v.w) << 16);
            ((uint2*)xb)[i] = o;
        } else {
            ((uint2*)xb)[i] = ((const uint2*)xin)[i];
        }
    } else {
        int i = (blockIdx.x - nbx) * 256 + threadIdx.x;
        if (i >= total) return;
        const void* src; int base;
        if      (i < o1) { src = s0; base = 0;  }
        else if (i < o2) { src = s1; base = o1; }
        else if (i < o3) { src = s2; base = o2; }
        else if (i < o4) { src = s3; base = o3; }
        else if (i < o5) { src = s4; base = o4; }
        else if (i < o6) { src = s5; base = o5; }
        else if (i < o7) { src = s6; base = o6; }
        else if (i < o8) { src = s7; base = o7; }
        else             { src = s8; base = o8; }
        int li = i - base;
        wdst[i] = fl ? f2bf(((const float*)src)[li]) : ((const unsigned short*)src)[li];
    }
}

// ---------------- OLD gemm core (LDS transpose) — only used by gemm_compose (8 blocks) ----------------
__device__ __forceinline__ void gemm_core(
    const unsigned short* __restrict__ A, const unsigned short* __restrict__ W,
    int M, int blockRow, unsigned short* As, unsigned short* Wt, f32x4 (&acc)[2][8])
{
    int t = threadIdx.x;
    #pragma unroll
    for (int i = 0; i < 8; ++i) {
        int ch = t + i * 256;
        int row = ch >> 4;
        int kc  = ch & 15;
        int grow = blockRow + row;
        uint4 v = make_uint4(0u, 0u, 0u, 0u);
        if (grow < M) v = *((const uint4*)(A + (size_t)grow * D + kc * 8));
        int kcs = kc ^ (row & 15);
        *((uint4*)&As[row * 128 + kcs * 8]) = v;
    }
    #pragma unroll
    for (int i = 0; i < 8; ++i) {
        int ch = t + i * 256;
        int k  = ch >> 4;
        int n0 = (ch & 15) * 8;
        uint4 v = *((const uint4*)(W + k * D + n0));
        const unsigned short* pv = (const unsigned short*)&v;
        int kc = k >> 3;
        int ko = k & 7;
        #pragma unroll
        for (int j = 0; j < 8; ++j) {
            int n = n0 + j;
            Wt[n * 128 + ((kc ^ (n & 15)) * 8) + ko] = pv[j];
        }
    }
    __syncthreads();

    int wave = t >> 6, lane = t & 63, quad = lane >> 4, l16 = lane & 15;
    int rowbase = wave * 32;

    #pragma unroll
    for (int a = 0; a < 2; ++a)
        #pragma unroll
        for (int b = 0; b < 8; ++b) acc[a][b] = (f32x4){0.f, 0.f, 0.f, 0.f};

    #pragma unroll
    for (int ks = 0; ks < 4; ++ks) {
        int chunk = ks * 4 + quad;
        short8 af[2];
        short8 bf[8];
        #pragma unroll
        for (int rt = 0; rt < 2; ++rt) {
            int r = rowbase + rt * 16 + l16;
            af[rt] = *((const short8*)&As[r * 128 + (chunk ^ (r & 15)) * 8]);
        }
        #pragma unroll
        for (int ct = 0; ct < 8; ++ct) {
            int n = ct * 16 + l16;
            bf[ct] = *((const short8*)&Wt[n * 128 + (chunk ^ (n & 15)) * 8]);
        }
        #pragma unroll
        for (int rt = 0; rt < 2; ++rt)
            #pragma unroll
            for (int ct = 0; ct < 8; ++ct)
                acc[rt][ct] = __builtin_amdgcn_mfma_f32_16x16x32_bf16(af[rt], bf[ct], acc[rt][ct], 0, 0, 0);
    }
}

__device__ __forceinline__ void store_c(
    f32x4 (&acc)[2][8], const unsigned short* __restrict__ bias,
    unsigned short* __restrict__ C, int M, int blockRow, int ldc, int coloff)
{
    int t = threadIdx.x;
    int wave = t >> 6, lane = t & 63, quad = lane >> 4, l16 = lane & 15;
    int rowbase = wave * 32;
    #pragma unroll
    for (int rt = 0; rt < 2; ++rt) {
        #pragma unroll
        for (int ct = 0; ct < 8; ++ct) {
            int col = ct * 16 + l16;
            float bv = bias ? bf2f(bias[col]) : 0.f;
            #pragma unroll
            for (int r = 0; r < 4; ++r) {
                int grow = blockRow + rowbase + rt * 16 + quad * 4 + r;
                if (grow < M) {
                    float v = acc[rt][ct][r] + bv;
                    C[(size_t)grow * ldc + coloff + col] = f2bf(v);
                }
            }
        }
    }
}

// ---------------- weight composition: Wc[b] = win_w[l] @ wrel[b], bc[b] = win_b[l] @ wrel[b] ----------------
__global__ __launch_bounds__(256) void gemm_compose(
    const unsigned short* __restrict__ w_in, const unsigned short* __restrict__ wrel,
    const unsigned short* __restrict__ b_in, unsigned short* __restrict__ wc,
    unsigned short* __restrict__ bc)
{
    __shared__ unsigned short As[DD];
    __shared__ unsigned short Wt[DD];
    f32x4 acc[2][8];
    int b = blockIdx.x;          // l*4 + r
    int l = b >> 2;
    const unsigned short* A = w_in + (size_t)l * DD;
    const unsigned short* W = wrel + (size_t)b * DD;
    gemm_core(A, W, 128, 0, As, Wt, acc);
    store_c(acc, nullptr, wc + (size_t)b * DD, 128, 0, D, 0);
    int t = threadIdx.x;
    if (t < 128) {
        float s = 0.f;
        for (int k = 0; k < 128; ++k)
            s += bf2f(b_in[l * D + k]) * bf2f(W[k * D + t]);
        bc[b * D + t] = f2bf(s);
    }
}

// ---------------- pre-transpose + swizzle 13 weight mats ----------------
__global__ __launch_bounds__(256) void k_prepw(
    const unsigned short* __restrict__ wbase, const unsigned short* __restrict__ wc,
    unsigned short* __restrict__ wtg, int o4, int o7)
{
    int m = blockIdx.x >> 3;
    int sub = blockIdx.x & 7;
    const unsigned short* src;
    if (m == 0)       src = wbase;                         // w_proj
    else if (m <= 2)  src = wbase + o4 + (m - 1) * DD;     // w_in[l]
    else if (m <= 10) src = wc + (size_t)(m - 3) * DD;     // composed wc[l*4+r]
    else              src = wbase + o7 + (m - 11) * DD;    // w_out[l]
    int c = sub * 256 + threadIdx.x;   // 0..2047
    int n = c >> 4;
    int kc = c & 15;
    unsigned short tmp[8];
    #pragma unroll
    for (int ko = 0; ko < 8; ++ko) tmp[ko] = src[(kc * 8 + ko) * 128 + n];
    *((uint4*)(wtg + (size_t)m * DD + n * 128 + ((kc ^ (n & 15)) * 8))) = *(uint4*)tmp;
}

// ---------------- FAST gemm core: W pre-transposed/swizzled, A direct from global ----------------
__device__ __forceinline__ void load_afrag(
    const unsigned short* __restrict__ A, int M, int blockRow, short8 (&af)[2][4])
{
    int t = threadIdx.x;
    int wave = t >> 6, lane = t & 63, quad = lane >> 4, l16 = lane & 15;
    int rowbase = blockRow + wave * 32;
    int r0 = min(rowbase + l16, M - 1);
    int r1 = min(rowbase + 16 + l16, M - 1);
    const unsigned short* a0 = A + (size_t)r0 * D;
    const unsigned short* a1 = A + (size_t)r1 * D;
    #pragma unroll
    for (int ks = 0; ks < 4; ++ks) {
        int chunk = ks * 4 + quad;
        af[0][ks] = *((const short8*)(a0 + chunk * 8));
        af[1][ks] = *((const short8*)(a1 + chunk * 8));
    }
}

__device__ __forceinline__ void mfma_slice(
    const unsigned short* Wt, short8 (&af)[2][4], f32x4 (&acc)[2][8])
{
    int lane = threadIdx.x & 63, quad = lane >> 4, l16 = lane & 15;
    #pragma unroll
    for (int a = 0; a < 2; ++a)
        #pragma unroll
        for (int b = 0; b < 8; ++b) acc[a][b] = (f32x4){0.f, 0.f, 0.f, 0.f};
    #pragma unroll
    for (int ks = 0; ks < 4; ++ks) {
        int chunk = ks * 4 + quad;
        short8 bf[8];
        #pragma unroll
        for (int ct = 0; ct < 8; ++ct)
            bf[ct] = *((const short8*)&Wt[(ct * 16 + l16) * 128 + ((chunk ^ l16) * 8)]);
        #pragma unroll
        for (int rt = 0; rt < 2; ++rt)
            #pragma unroll
            for (int ct = 0; ct < 8; ++ct)
                acc[rt][ct] = __builtin_amdgcn_mfma_f32_16x16x32_bf16(af[rt][ks], bf[ct], acc[rt][ct], 0, 0, 0);
    }
}

__device__ __forceinline__ void gemm_core_fast(
    const unsigned short* __restrict__ A,
    const unsigned short* __restrict__ Wt_g,
    int M, int blockRow, unsigned short* Wt, f32x4 (&acc)[2][8])
{
    int t = threadIdx.x;
    #pragma unroll
    for (int i = 0; i < 8; ++i)
        ((uint4*)Wt)[t + i * 256] = ((const uint4*)Wt_g)[t + i * 256];
    short8 af[2][4];
    load_afrag(A, M, blockRow, af);
    __syncthreads();
    mfma_slice(Wt, af, acc);
}

// ---------------- plain fast GEMM ----------------
__global__ __launch_bounds__(256) void gemm_fast(
    const unsigned short* __restrict__ A, const unsigned short* __restrict__ Wt_g,
    const unsigned short* __restrict__ bias, unsigned short* __restrict__ C,
    int M, int ldc, int coloff)
{
    __shared__ unsigned short Wt[DD];
    f32x4 acc[2][8];
    gemm_core_fast(A, Wt_g, M, blockIdx.x * 128, Wt, acc);
    store_c(acc, bias, C, M, blockIdx.x * 128, ldc, coloff);
}

// ---------------- proj GEMM + per-block BN partial stats ----------------
__global__ __launch_bounds__(256) void gemm_proj(
    const unsigned short* __restrict__ A, const unsigned short* __restrict__ Wt_g,
    const unsigned short* __restrict__ bias, unsigned short* __restrict__ C,
    int M, float* __restrict__ psum, float* __restrict__ psq)
{
    __shared__ unsigned short Wt[DD];
    __shared__ float smS[4][128], smQ[4][128];
    f32x4 acc[2][8];
    int blockRow = blockIdx.x * 128;
    gemm_core_fast(A, Wt_g, M, blockRow, Wt, acc);

    int t = threadIdx.x;
    int wave = t >> 6, lane = t & 63, quad = lane >> 4, l16 = lane & 15;
    int rowbase = wave * 32;
    #pragma unroll
    for (int ct = 0; ct < 8; ++ct) {
        int col = ct * 16 + l16;
        float bv = bf2f(bias[col]);
        float ps = 0.f, pq = 0.f;
        #pragma unroll
        for (int rt = 0; rt < 2; ++rt) {
            #pragma unroll
            for (int r = 0; r < 4; ++r) {
                int grow = blockRow + rowbase + rt * 16 + quad * 4 + r;
                if (grow < M) {
                    float v = acc[rt][ct][r] + bv;
                    C[(size_t)grow * D + col] = f2bf(v);
                    ps += v; pq += v * v;
                }
            }
        }
        ps += __shfl_xor(ps, 16, 64); ps += __shfl_xor(ps, 32, 64);
        pq += __shfl_xor(pq, 16, 64); pq += __shfl_xor(pq, 32, 64);
        if (quad == 0) { smS[wave][col] = ps; smQ[wave][col] = pq; }
    }
    __syncthreads();
    if (t < 128) {
        float s = smS[0][t] + smS[1][t] + smS[2][t] + smS[3][t];
        float q = smQ[0][t] + smQ[1][t] + smQ[2][t] + smQ[3][t];
        psum[blockIdx.x * 128 + t] = s;
        psq[blockIdx.x * 128 + t] = q;
    }
}

// ---------------- per-layer fused GEMM: A loaded once, slices phased through one LDS buffer ----------------
// blockIdx.y==0 -> slices {0,1}; blockIdx.y==1 -> slices {2,3,4}
// slice 0: xl = (h@W1+b1)*dinv (row-scaled); slice r>=1: y[r-1][node] = h@Wc_r+bc_r
__global__ __launch_bounds__(256) void gemm_fused5(
    const unsigned short* __restrict__ h, const unsigned short* __restrict__ wtg,
    const unsigned short* __restrict__ b_in_l, const unsigned short* __restrict__ bc_l,
    unsigned short* __restrict__ xl, unsigned short* __restrict__ y,
    const float* __restrict__ dinv, int M, int Ntot, int l)
{
    __shared__ unsigned short Wt[DD];
    int t = threadIdx.x;
    int blockRow = blockIdx.x * 128;
    short8 af[2][4];
    load_afrag(h, M, blockRow, af);
    int s0 = (blockIdx.y == 0) ? 0 : 2;
    int s1 = (blockIdx.y == 0) ? 2 : 5;
    int wave = t >> 6, lane = t & 63, quad = lane >> 4, l16 = lane & 15;
    int rowbase = wave * 32;
    for (int slice = s0; slice < s1; ++slice) {
        int m = (slice == 0) ? (1 + l) : (3 + l * 4 + slice - 1);
        const unsigned short* Wt_g = wtg + (size_t)m * DD;
        #pragma unroll
        for (int i = 0; i < 8; ++i)
            ((uint4*)Wt)[t + i * 256] = ((const uint4*)Wt_g)[t + i * 256];
        __syncthreads();
        f32x4 acc[2][8];
        mfma_slice(Wt, af, acc);
        if (slice == 0) {
            #pragma unroll
            for (int rt = 0; rt < 2; ++rt) {
                float dv[4];
                #pragma unroll
                for (int r = 0; r < 4; ++r) {
                    int grow = min(blockRow + rowbase + rt * 16 + quad * 4 + r, M - 1);
                    dv[r] = dinv[grow];
                }
                #pragma unroll
                for (int ct = 0; ct < 8; ++ct) {
                    int col = ct * 16 + l16;
                    float bv = bf2f(b_in_l[col]);
                    #pragma unroll
                    for (int r = 0; r < 4; ++r) {
                        int grow = blockRow + rowbase + rt * 16 + quad * 4 + r;
                        if (grow < M)
                            xl[(size_t)grow * D + col] = f2bf((acc[rt][ct][r] + bv) * dv[r]);
                    }
                }
            }
        } else {
            store_c(acc, bc_l + (slice - 1) * D, y + (size_t)(slice - 1) * Ntot * D,
                    M, blockRow, D, 0);
        }
        __syncthreads();
    }
}

// ---------------- final GEMM on compact zg rows + exact GeLU epilogue ----------------
__global__ __launch_bounds__(256) void gemm_out(
    const unsigned short* __restrict__ zg, const unsigned short* __restrict__ Wt_g,
    const unsigned short* __restrict__ bias, void* __restrict__ out,
    int M, const unsigned short* __restrict__ xprobe)
{
    int fl = vote_flag(xprobe);
    __shared__ unsigned short Wt[DD];
    f32x4 acc[2][8];
    int blockRow = blockIdx.x * 128;
    gemm_core_fast(zg, Wt_g, M, blockRow, Wt, acc);
    int t = threadIdx.x;
    int wave = t >> 6, lane = t & 63, quad = lane >> 4, l16 = lane & 15;
    int rowbase = wave * 32;
    #pragma unroll
    for (int rt = 0; rt < 2; ++rt) {
        #pragma unroll
        for (int ct = 0; ct < 8; ++ct) {
            int col = ct * 16 + l16;
            float bv = bf2f(bias[col]);
            #pragma unroll
            for (int r = 0; r < 4; ++r) {
                int grow = blockRow + rowbase + rt * 16 + quad * 4 + r;
                if (grow < M) {
                    float v = acc[rt][ct][r] + bv;
                    float gl = 0.5f * v * (1.f + erff(v * 0.70710678118654752f));
                    size_t o = (size_t)grow * D + col;
                    if (fl) ((float*)out)[o] = gl;
                    else    ((unsigned short*)out)[o] = f2bf(gl);
                }
            }
        }
    }
}

// ================= atomic-free CSR build via single-digit bucket sort =================
__global__ __launch_bounds__(256) void k_hista(
    const int* __restrict__ ei, int E,
    unsigned int* __restrict__ part_dst, unsigned int* __restrict__ part_src)
{
    __shared__ unsigned int hd[256], hs[256];
    int b = blockIdx.x, t = threadIdx.x;
    hd[t] = 0u; hs[t] = 0u;
    __syncthreads();
    int base = b * 2048;
    #pragma unroll
    for (int i = 0; i < 8; ++i) {
        int e = base + t + i * 256;
        if (e < E) {
            atomicAdd(&hd[((unsigned int)ei[e]) >> 8], 1u);
            atomicAdd(&hs[((unsigned int)ei[E + e]) >> 8], 1u);
        }
    }
    __syncthreads();
    part_dst[b * 256 + t] = hd[t];
    part_src[b * 256 + t] = hs[t];
}

__global__ void k_scanpart(unsigned int* __restrict__ part_d, unsigned int* __restrict__ part_s,
                           unsigned int* __restrict__ btot_d, unsigned int* __restrict__ btot_s,
                           int BA)
{
    __shared__ unsigned int arr[512];
    unsigned int* part = blockIdx.y ? part_s : part_d;
    unsigned int* btot = blockIdx.y ? btot_s : btot_d;
    int bucket = blockIdx.x, t = threadIdx.x;
    unsigned int v0 = (t < BA) ? part[t * 256 + bucket] : 0u;
    unsigned int v1 = (t + 256 < BA) ? part[(t + 256) * 256 + bucket] : 0u;
    arr[t] = v0; arr[t + 256] = v1;
    __syncthreads();
    for (int off = 1; off < 512; off <<= 1) {
        unsigned int a = arr[t], b2 = arr[t + 256];
        unsigned int pa = (t >= off) ? arr[t - off] : 0u;
        unsigned int pb = (t + 256 >= off) ? arr[t + 256 - off] : 0u;
        __syncthreads();
        arr[t] = a + pa; arr[t + 256] = b2 + pb;
        __syncthreads();
    }
    if (t < BA) part[t * 256 + bucket] = arr[t] - v0;
    if (t + 256 < BA) part[(t + 256) * 256 + bucket] = arr[t + 256] - v1;
    if (t == 0) btot[bucket] = arr[511];
}

__global__ void k_scanbase(const unsigned int* __restrict__ btot_d, const unsigned int* __restrict__ btot_s,
                           unsigned int* __restrict__ bbase_d, unsigned int* __restrict__ bbase_s)
{
    __shared__ unsigned int a1[256], a2[256];
    int t = threadIdx.x;
    unsigned int vd = btot_d[t], vs = btot_s[t];
    a1[t] = vd; a2[t] = vs;
    __syncthreads();
    for (int off = 1; off < 256; off <<= 1) {
        unsigned int x = a1[t], y = a2[t];
        unsigned int px = (t >= off) ? a1[t - off] : 0u;
        unsigned int py = (t >= off) ? a2[t - off] : 0u;
        __syncthreads();
        a1[t] = x + px; a2[t] = y + py;
        __syncthreads();
    }
    bbase_d[t] = a1[t] - vd;
    bbase_s[t] = a2[t] - vs;
    if (t == 255) { bbase_d[256] = a1[255]; bbase_s[256] = a2[255]; }
}

__global__ __launch_bounds__(256) void k_bscatter(
    const int* __restrict__ ei, const int* __restrict__ et, int E,
    const unsigned int* __restrict__ part_dst, const unsigned int* __restrict__ part_src,
    const unsigned int* __restrict__ bbase_d, const unsigned int* __restrict__ bbase_s,
    uint2* __restrict__ ebuck, unsigned short* __restrict__ sbuck)
{
    __shared__ unsigned int cd[256], cs[256];
    int b = blockIdx.x, t = threadIdx.x;
    cd[t] = part_dst[b * 256 + t] + bbase_d[t];
    cs[t] = part_src[b * 256 + t] + bbase_s[t];
    __syncthreads();
    int base = b * 2048;
    #pragma unroll
    for (int i = 0; i < 8; ++i) {
        int e = base + t + i * 256;
        if (e < E) {
            unsigned int d = (unsigned int)ei[e];
            unsigned int s = (unsigned int)ei[E + e];
            unsigned int tt = (unsigned int)et[e];
            unsigned int pd = atomicAdd(&cd[d >> 8], 1u);
            ebuck[pd] = make_uint2(d, s | (tt << 16));
            unsigned int ps = atomicAdd(&cs[s >> 8], 1u);
            sbuck[ps] = (unsigned short)s;
        }
    }
}

// y=0: per-dst-bucket counting sort on key (dloc<<2|type) -> rp + type-subsorted pckd
// y=1: per-src-bucket histogram -> dinv
__global__ __launch_bounds__(256) void k_buckets(
    const unsigned int* __restrict__ bbase_d, const uint2* __restrict__ ebuck,
    unsigned int* __restrict__ rp, unsigned int* __restrict__ pckd,
    const unsigned int* __restrict__ bbase_s, const unsigned short* __restrict__ sbuck,
    float* __restrict__ dinv, int N)
{
    __shared__ uint2 ebuf[BCAP];
    __shared__ unsigned int bins[1024], gsum[256];
    int b = blockIdx.x, t = threadIdx.x;
    if (blockIdx.y == 0) {
        unsigned int beg = bbase_d[b], end = bbase_d[b + 1];
        unsigned int cnt = end - beg;
        #pragma unroll
        for (int j = 0; j < 4; ++j) bins[t + j * 256] = 0u;
        __syncthreads();
        bool fit = cnt <= (unsigned int)BCAP;
        if (fit) {
            for (unsigned int i = t; i < cnt; i += 256) {
                uint2 v = ebuck[beg + i];
                ebuf[i] = v;
                atomicAdd(&bins[((v.x & 255u) << 2) | ((v.y >> 16) & 3u)], 1u);
            }
        } else {
            for (unsigned int i = t; i < cnt; i += 256) {
                uint2 v = ebuck[beg + i];
                atomicAdd(&bins[((v.x & 255u) << 2) | ((v.y >> 16) & 3u)], 1u);
            }
        }
        __syncthreads();
        unsigned int b0 = bins[4 * t], b1 = bins[4 * t + 1], b2 = bins[4 * t + 2], b3 = bins[4 * t + 3];
        unsigned int s4 = b0 + b1 + b2 + b3;
        gsum[t] = s4;
        __syncthreads();
        for (int off = 1; off < 256; off <<= 1) {
            unsigned int v = gsum[t];
            unsigned int a = (t >= off) ? gsum[t - off] : 0u;
            __syncthreads();
            gsum[t] = v + a;
            __syncthreads();
        }
        unsigned int base0 = gsum[t] - s4;
        bins[4 * t]     = base0;
        bins[4 * t + 1] = base0 + b0;
        bins[4 * t + 2] = base0 + b0 + b1;
        bins[4 * t + 3] = base0 + b0 + b1 + b2;
        int n = (b << 8) + t;
        if (n <= N) rp[n] = beg + base0;
        __syncthreads();
        if (fit) {
            for (unsigned int i = t; i < cnt; i += 256) {
                uint2 v = ebuf[i];
                unsigned int key = ((v.x & 255u) << 2) | ((v.y >> 16) & 3u);
                unsigned int pos = beg + atomicAdd(&bins[key], 1u);
                pckd[pos] = v.y;
            }
        } else {
            for (unsigned int i = t; i < cnt; i += 256) {
                uint2 v = ebuck[beg + i];
                unsigned int key = ((v.x & 255u) << 2) | ((v.y >> 16) & 3u);
                unsigned int pos = beg + atomicAdd(&bins[key], 1u);
                pckd[pos] = v.y;
            }
        }
    } else {
        unsigned int beg = bbase_s[b], end = bbase_s[b + 1];
        bins[t] = 0u;
        __syncthreads();
        for (unsigned int i = beg + t; i < end; i += 256)
            atomicAdd(&bins[sbuck[i] & 255u], 1u);
        __syncthreads();
        int n = (b << 8) + t;
        if (n < N) {
            unsigned int dg = bins[t];
            dinv[n] = dg ? rsqrtf((float)dg) : 0.f;
        }
    }
}

// ---------------- BN stats reduce (1 block) ----------------
__global__ void k_bnstats(const float* __restrict__ psum, const float* __restrict__ psq,
                          int nb, int N, const unsigned short* __restrict__ g,
                          const unsigned short* __restrict__ b,
                          float* __restrict__ scale, float* __restrict__ shift) {
    int col = threadIdx.x & 127, h = threadIdx.x >> 7;
    float s = 0.f, q = 0.f;
    for (int i = h; i < nb; i += 2) { s += psum[i * 128 + col]; q += psq[i * 128 + col]; }
    __shared__ float sS[256], sQ[256];
    sS[threadIdx.x] = s; sQ[threadIdx.x] = q;
    __syncthreads();
    if (h == 0) {
        s = sS[col] + sS[col + 128];
        q = sQ[col] + sQ[col + 128];
        float inv = 1.f / (float)N;
        float mean = s * inv;
        float var = fmaxf(q * inv - mean * mean, 0.f);
        float sc = rsqrtf(var + 1e-5f) * bf2f(g[col]);
        scale[col] = sc;
        shift[col] = bf2f(b[col]) - mean * sc;
    }
}

// ---------------- BN apply + relu (vec 8 shorts/thread) ----------------
__global__ void k_bnrelu(unsigned short* __restrict__ h, const float* __restrict__ scale,
                         const float* __restrict__ shift, int n8) {
    int i = blockIdx.x * blockDim.x + threadIdx.x;
    if (i >= n8) return;
    int cb = (i & 15) * 8;
    uint4 v = ((uint4*)h)[i];
    unsigned int* w = (unsigned int*)&v;
    #pragma unroll
    for (int j = 0; j < 4; ++j) {
        int c = cb + j * 2;
        float v0 = __uint_as_float(w[j] << 16);
        float v1 = __uint_as_float(w[j] & 0xFFFF0000u);
        v0 = fmaxf(fmaf(v0, scale[c], shift[c]), 0.f);
        v1 = fmaxf(fmaf(v1, scale[c + 1], shift[c + 1]), 0.f);
        w[j] = (unsigned int)f2bf(v0) | ((unsigned int)f2bf(v1) << 16);
    }
    ((uint4*)h)[i] = v;
}

// ---------------- edge aggregation: 1 wave/node, 16 edges in flight, exec-masked tail ----------------
__device__ __forceinline__ void acc_edge(uint4 xv, uint4 yv, float vm,
                                         float* g, float* dd, float* ss) {
    const unsigned int* xw = (const unsigned int*)&xv;
    const unsigned int* yw = (const unsigned int*)&yv;
    #pragma unroll
    for (int w = 0; w < 4; ++w) {
        float x0 = __uint_as_float(xw[w] << 16);
        float x1 = __uint_as_float(xw[w] & 0xFFFF0000u);
        float v0 = __uint_as_float(yw[w] << 16);
        float v1 = __uint_as_float(yw[w] & 0xFFFF0000u);
        int j0 = 2 * w, j1 = 2 * w + 1;
        g[j0] += x0;
        g[j1] += x1;
        float e0 = __expf(v0), e1 = __expf(v1);
        dd[j0] = fmaf(e0, vm, dd[j0]);
        dd[j1] = fmaf(e1, vm, dd[j1]);
        ss[j0] = fmaf(v0 * e0, vm, ss[j0]);
        ss[j1] = fmaf(v1 * e1, vm, ss[j1]);
    }
}

__global__ __launch_bounds__(256) void k_edge(
    const unsigned int* __restrict__ rp, const unsigned int* __restrict__ packed,
    const unsigned short* __restrict__ xl, const unsigned short* __restrict__ y,
    const float* __restrict__ dinv, unsigned short* __restrict__ zout,
    int NN, int Ntot, const int* __restrict__ nodes)
{
    int lane = threadIdx.x & 63;
    int slot = blockIdx.x * 4 + (threadIdx.x >> 6);
    if (slot >= NN) return;
    int node = nodes ? nodes[slot] : slot;
    node = __builtin_amdgcn_readfirstlane(node);
    unsigned int beg = rp[node], end = rp[node + 1];
    int eg = lane >> 4;
    int cb = (lane & 15) * 8;
    float g[8], dd[8], ss[8];
    #pragma unroll
    for (int j = 0; j < 8; ++j) { g[j] = 0.f; dd[j] = 0.f; ss[j] = 0.f; }

    for (unsigned int e0 = beg; e0 < end; e0 += 16) {
        uint4 xv[4], yv[4];
        float vm[4];
        #pragma unroll
        for (int u = 0; u < 4; ++u) {
            unsigned int e = e0 + u * 4 + (unsigned int)eg;
            bool valid = e < end;
            vm[u] = valid ? 1.f : 0.f;
            xv[u] = make_uint4(0u, 0u, 0u, 0u);
            yv[u] = make_uint4(0u, 0u, 0u, 0u);
            if (valid) {
                unsigned int p = packed[e];
                unsigned int s = p & 0xFFFFu;
                unsigned int tt = (p >> 16) & 3u;
                xv[u] = *((const uint4*)(xl + (size_t)s * D + cb));
                yv[u] = *((const uint4*)(y + ((size_t)tt * Ntot + s) * D + cb));
            }
        }
        #pragma unroll
        for (int u = 0; u < 4; ++u) acc_edge(xv[u], yv[u], vm[u], g, dd, ss);
    }

    #pragma unroll
    for (int j = 0; j < 8; ++j) {
        g[j]  += __shfl_xor(g[j], 16, 64);  g[j]  += __shfl_xor(g[j], 32, 64);
        dd[j] += __shfl_xor(dd[j], 16, 64); dd[j] += __shfl_xor(dd[j], 32, 64);
        ss[j] += __shfl_xor(ss[j], 16, 64); ss[j] += __shfl_xor(ss[j], 32, 64);
    }
    if (eg == 0) {
        float dn = dinv[node];
        unsigned int o[4];
        #pragma unroll
        for (int w = 0; w < 4; ++w) {
            int j0 = w * 2, j1 = w * 2 + 1;
            float m0 = (dd[j0] > 0.f) ? ss[j0] / dd[j0] : 0.f;
            float m1 = (dd[j1] > 0.f) ? ss[j1] / dd[j1] : 0.f;
            float z0 = fmaf(g[j0], dn, 0.1f * fmaxf(m0, 0.f));
            float z1 = fmaf(g[j1], dn, 0.1f * fmaxf(m1, 0.f));
            o[w] = (unsigned int)f2bf(z0) | ((unsigned int)f2bf(z1) << 16);
        }
        *((uint4*)(zout + (size_t)slot * D + cb)) = *(uint4*)o;
    }
}

extern "C" void kernel_launch(void* const* d_in, const int* in_sizes, int n_in,
                              void* d_out, int out_size, void* d_ws, size_t ws_size,
                              hipStream_t stream)
{
    const int* ei  = (const int*)d_in[1];
    const int* idx = (const int*)d_in[2];
    const int* et  = (const int*)d_in[3];
    const unsigned short* xprobe = (const unsigned short*)d_in[0];

    int N  = in_sizes[0] / D;            // 48758
    int E  = in_sizes[1] / 2;            // 780000
    int NI = in_sizes[2];                // 10000
    int L  = in_sizes[9] / (D * D);      // 2
    int R  = in_sizes[11] / (L * D * D); // 4

    int NB = (N + 255) >> 8;             // dst/src buckets
    int BA = (E + 2047) / 2048;          // histogram/scatter blocks

    char* ws = (char*)d_ws;
    size_t off = 0;
    auto alloc = [&](size_t bytes) -> char* {
        char* p = ws + off;
        off += (bytes + 255) & ~(size_t)255;
        return p;
    };
    unsigned short* h    = (unsigned short*)alloc((size_t)N * D * 2);
    unsigned short* xl   = (unsigned short*)alloc((size_t)N * D * 2);
    unsigned short* y    = (unsigned short*)alloc((size_t)N * R * D * 2);  // [type][node][D]
    unsigned short* z    = (unsigned short*)alloc((size_t)N * D * 2);
    unsigned short* xb   = (unsigned short*)alloc((size_t)N * D * 2);
    unsigned short* zg   = (unsigned short*)alloc((size_t)NI * D * 2);
    float*          dinv = (float*)alloc((size_t)N * 4);
    unsigned int*   rp   = (unsigned int*)alloc((size_t)(N + 1) * 4);
    unsigned int*   pckd = (unsigned int*)alloc((size_t)E * 4);
    int gb  = (N + 127) / 128;
    float*          psum = (float*)alloc((size_t)gb * 128 * 4);
    float*          psq  = (float*)alloc((size_t)gb * 128 * 4);
    float*          bscale = (float*)alloc(128 * 4);
    float*          bshift = (float*)alloc(128 * 4);
    // bucket-sort scratch
    unsigned int*   part_dst = (unsigned int*)alloc((size_t)BA * 256 * 4);
    unsigned int*   part_src = (unsigned int*)alloc((size_t)BA * 256 * 4);
    unsigned int*   btot_d   = (unsigned int*)alloc(256 * 4);
    unsigned int*   btot_s   = (unsigned int*)alloc(256 * 4);
    unsigned int*   bbase_d  = (unsigned int*)alloc(257 * 4);
    unsigned int*   bbase_s  = (unsigned int*)alloc(257 * 4);
    // aliases into regions dead during graph prep
    uint2*          ebuck = (uint2*)y;           // E*8 <= N*R*D*2
    unsigned short* sbuck = (unsigned short*)z;  // E*2 <= N*D*2
    // contiguous bf16 weight region
    int o1 = D * D;                // w_proj
    int o2 = o1 + D;               // b_proj
    int o3 = o2 + D;               // bn_g
    int o4 = o3 + D;               // bn_b
    int o5 = o4 + L * D * D;       // w_in
    int o6 = o5 + L * D;           // b_in
    int o7 = o6 + L * R * D * D;   // w_rel
    int o8 = o7 + L * D * D;       // w_out
    int wt = o8 + L * D;           // b_out end
    unsigned short* wbase  = (unsigned short*)alloc((size_t)wt * 2);
    unsigned short* b_proj = wbase + o1;
    unsigned short* g_bn   = wbase + o2;
    unsigned short* b_bn   = wbase + o3;
    unsigned short* w_in   = wbase + o4;
    unsigned short* b_in   = wbase + o5;
    unsigned short* w_rel  = wbase + o6;
    unsigned short* b_out  = wbase + o8;
    unsigned short* wc     = (unsigned short*)alloc((size_t)L * R * D * D * 2);
    unsigned short* bc     = (unsigned short*)alloc((size_t)L * R * D * 2);
    unsigned short* wtg    = (unsigned short*)alloc((size_t)13 * DD * 2);
    (void)ws_size; (void)n_in; (void)out_size;

    int gb2 = (NI + 127) / 128;
    int nb4 = (N + 3) / 4;
    int ni4 = (NI + 3) / 4;

    // input normalization (dtype vote inline)
    int n4 = N * D / 4;
    int nbx = (n4 + 255) / 256;
    int nbw = (wt + 255) / 256;
    k_normall<<<nbx + nbw, 256, 0, stream>>>(
        d_in[0], xb, n4, nbx,
        d_in[5], d_in[6], d_in[7], d_in[8], d_in[9], d_in[10], d_in[11], d_in[12], d_in[13],
        o1, o2, o3, o4, o5, o6, o7, o8, wt, wbase);

    // atomic-free CSR build (type-subsorted per dst)
    k_hista<<<BA, 256, 0, stream>>>(ei, E, part_dst, part_src);
    k_scanpart<<<dim3(256, 2), 256, 0, stream>>>(part_dst, part_src, btot_d, btot_s, BA);
    k_scanbase<<<1, 256, 0, stream>>>(btot_d, btot_s, bbase_d, bbase_s);
    k_bscatter<<<BA, 256, 0, stream>>>(ei, et, E, part_dst, part_src, bbase_d, bbase_s, ebuck, sbuck);
    k_buckets<<<dim3(NB, 2), 256, 0, stream>>>(bbase_d, ebuck, rp, pckd, bbase_s, sbuck, dinv, N);

    // composed weights, then pre-transposed/swizzled GEMM weights
    gemm_compose<<<L * R, 256, 0, stream>>>(w_in, w_rel, b_in, wc, bc);
    k_prepw<<<13 * 8, 256, 0, stream>>>(wbase, wc, wtg, o4, o7);

    // proj + BN + relu
    gemm_proj<<<gb, 256, 0, stream>>>(xb, wtg, b_proj, h, N, psum, psq);
    k_bnstats<<<1, 256, 0, stream>>>(psum, psq, gb, N, g_bn, b_bn, bscale, bshift);
    int n8 = N * D / 8;
    k_bnrelu<<<(n8 + 255) / 256, 256, 0, stream>>>(h, bscale, bshift, n8);

    // layer 0 (full graph)
    gemm_fused5<<<dim3(gb, 2), 256, 0, stream>>>(h, wtg, b_in, bc, xl, y, dinv, N, N, 0);
    k_edge<<<nb4, 256, 0, stream>>>(rp, pckd, xl, y, dinv, z, N, N, nullptr);
    gemm_fast<<<gb, 256, 0, stream>>>(z, wtg + (size_t)11 * DD, b_out, h, N, D, 0);

    // layer 1 (aggregate only idx rows, compact output)
    gemm_fused5<<<dim3(gb, 2), 256, 0, stream>>>(h, wtg, b_in + D, bc + R * D, xl, y, dinv, N, N, 1);
    k_edge<<<ni4, 256, 0, stream>>>(rp, pckd, xl, y, dinv, zg, NI, N, idx);

    // final GEMM on compact rows + GeLU
    gemm_out<<<gb2, 256, 0, stream>>>(zg, wtg + (size_t)12 * DD, b_out + D, d_out, NI, xprobe);
}

// Round 9
// 362.377 us; speedup vs baseline: 1.1360x; 1.1360x over previous
//
#include <hip/hip_runtime.h>
#include <hip/hip_bf16.h>
#include <math.h>

#define D 128
#define DD (128 * 128)
#define BCAP 6400   // per-dst-bucket LDS edge capacity (avg 4096, sigma ~64)

typedef __attribute__((ext_vector_type(8))) short short8;
typedef __attribute__((ext_vector_type(4))) float f32x4;

__device__ __forceinline__ float bf2f(unsigned short u) {
    union { unsigned int i; float f; } x; x.i = ((unsigned int)u) << 16; return x.f;
}
__device__ __forceinline__ unsigned short f2bf(float f) {
    unsigned int i = __float_as_uint(f);
    unsigned int r = (i + 0x7FFFu + ((i >> 16) & 1u)) >> 16;  // RNE
    return (unsigned short)r;
}

// inline dtype vote: fp32 read as shorts -> ~50% random exponent fields. 256-thread blocks.
__device__ __forceinline__ int vote_flag(const unsigned short* __restrict__ x) {
    __shared__ int bad_s;
    if (threadIdx.x == 0) bad_s = 0;
    __syncthreads();
    unsigned int e = (x[threadIdx.x] >> 7) & 0xFFu;
    unsigned long long b = __ballot(e < 100u || e > 140u);
    if ((threadIdx.x & 63) == 0) atomicAdd(&bad_s, __popcll(b));
    __syncthreads();
    return bad_s > 48 ? 1 : 0;
}

// ---------------- normalize x (vec4) + all 9 weight tensors, one kernel ----------------
__global__ __launch_bounds__(256) void k_normall(
    const void* __restrict__ xin, unsigned short* __restrict__ xb, int n4, int nbx,
    const void* s0, const void* s1, const void* s2, const void* s3,
    const void* s4, const void* s5, const void* s6, const void* s7, const void* s8,
    int o1, int o2, int o3, int o4, int o5, int o6, int o7, int o8,
    int total, unsigned short* __restrict__ wdst)
{
    int fl = vote_flag((const unsigned short*)xin);
    if (blockIdx.x < nbx) {
        int i = blockIdx.x * 256 + threadIdx.x;
        if (i >= n4) return;
        if (fl) {
            float4 v = ((const float4*)xin)[i];
            uint2 o;
            o.x = (unsigned int)f2bf(v.x) | ((unsigned int)f2bf(v.y) << 16);
            o.y = (unsigned int)f2bf(v.z) | ((unsigned int)f2bf(v.w) << 16);
            ((uint2*)xb)[i] = o;
        } else {
            ((uint2*)xb)[i] = ((const uint2*)xin)[i];
        }
    } else {
        int i = (blockIdx.x - nbx) * 256 + threadIdx.x;
        if (i >= total) return;
        const void* src; int base;
        if      (i < o1) { src = s0; base = 0;  }
        else if (i < o2) { src = s1; base = o1; }
        else if (i < o3) { src = s2; base = o2; }
        else if (i < o4) { src = s3; base = o3; }
        else if (i < o5) { src = s4; base = o4; }
        else if (i < o6) { src = s5; base = o5; }
        else if (i < o7) { src = s6; base = o6; }
        else if (i < o8) { src = s7; base = o7; }
        else             { src = s8; base = o8; }
        int li = i - base;
        wdst[i] = fl ? f2bf(((const float*)src)[li]) : ((const unsigned short*)src)[li];
    }
}

// ---------------- OLD gemm core (LDS transpose) — only used by gemm_compose (8 blocks) ----------------
__device__ __forceinline__ void gemm_core(
    const unsigned short* __restrict__ A, const unsigned short* __restrict__ W,
    int M, int blockRow, unsigned short* As, unsigned short* Wt, f32x4 (&acc)[2][8])
{
    int t = threadIdx.x;
    #pragma unroll
    for (int i = 0; i < 8; ++i) {
        int ch = t + i * 256;
        int row = ch >> 4;
        int kc  = ch & 15;
        int grow = blockRow + row;
        uint4 v = make_uint4(0u, 0u, 0u, 0u);
        if (grow < M) v = *((const uint4*)(A + (size_t)grow * D + kc * 8));
        int kcs = kc ^ (row & 15);
        *((uint4*)&As[row * 128 + kcs * 8]) = v;
    }
    #pragma unroll
    for (int i = 0; i < 8; ++i) {
        int ch = t + i * 256;
        int k  = ch >> 4;
        int n0 = (ch & 15) * 8;
        uint4 v = *((const uint4*)(W + k * D + n0));
        const unsigned short* pv = (const unsigned short*)&v;
        int kc = k >> 3;
        int ko = k & 7;
        #pragma unroll
        for (int j = 0; j < 8; ++j) {
            int n = n0 + j;
            Wt[n * 128 + ((kc ^ (n & 15)) * 8) + ko] = pv[j];
        }
    }
    __syncthreads();

    int wave = t >> 6, lane = t & 63, quad = lane >> 4, l16 = lane & 15;
    int rowbase = wave * 32;

    #pragma unroll
    for (int a = 0; a < 2; ++a)
        #pragma unroll
        for (int b = 0; b < 8; ++b) acc[a][b] = (f32x4){0.f, 0.f, 0.f, 0.f};

    #pragma unroll
    for (int ks = 0; ks < 4; ++ks) {
        int chunk = ks * 4 + quad;
        short8 af[2];
        short8 bf[8];
        #pragma unroll
        for (int rt = 0; rt < 2; ++rt) {
            int r = rowbase + rt * 16 + l16;
            af[rt] = *((const short8*)&As[r * 128 + (chunk ^ (r & 15)) * 8]);
        }
        #pragma unroll
        for (int ct = 0; ct < 8; ++ct) {
            int n = ct * 16 + l16;
            bf[ct] = *((const short8*)&Wt[n * 128 + (chunk ^ (n & 15)) * 8]);
        }
        #pragma unroll
        for (int rt = 0; rt < 2; ++rt)
            #pragma unroll
            for (int ct = 0; ct < 8; ++ct)
                acc[rt][ct] = __builtin_amdgcn_mfma_f32_16x16x32_bf16(af[rt], bf[ct], acc[rt][ct], 0, 0, 0);
    }
}

__device__ __forceinline__ void store_c(
    f32x4 (&acc)[2][8], const unsigned short* __restrict__ bias,
    unsigned short* __restrict__ C, int M, int blockRow, int ldc, int coloff)
{
    int t = threadIdx.x;
    int wave = t >> 6, lane = t & 63, quad = lane >> 4, l16 = lane & 15;
    int rowbase = wave * 32;
    #pragma unroll
    for (int rt = 0; rt < 2; ++rt) {
        #pragma unroll
        for (int ct = 0; ct < 8; ++ct) {
            int col = ct * 16 + l16;
            float bv = bias ? bf2f(bias[col]) : 0.f;
            #pragma unroll
            for (int r = 0; r < 4; ++r) {
                int grow = blockRow + rowbase + rt * 16 + quad * 4 + r;
                if (grow < M) {
                    float v = acc[rt][ct][r] + bv;
                    C[(size_t)grow * ldc + coloff + col] = f2bf(v);
                }
            }
        }
    }
}

// ---------------- weight composition: Wc[b] = win_w[l] @ wrel[b], bc[b] = win_b[l] @ wrel[b] ----------------
__global__ __launch_bounds__(256) void gemm_compose(
    const unsigned short* __restrict__ w_in, const unsigned short* __restrict__ wrel,
    const unsigned short* __restrict__ b_in, unsigned short* __restrict__ wc,
    unsigned short* __restrict__ bc)
{
    __shared__ unsigned short As[DD];
    __shared__ unsigned short Wt[DD];
    f32x4 acc[2][8];
    int b = blockIdx.x;          // l*4 + r
    int l = b >> 2;
    const unsigned short* A = w_in + (size_t)l * DD;
    const unsigned short* W = wrel + (size_t)b * DD;
    gemm_core(A, W, 128, 0, As, Wt, acc);
    store_c(acc, nullptr, wc + (size_t)b * DD, 128, 0, D, 0);
    int t = threadIdx.x;
    if (t < 128) {
        float s = 0.f;
        for (int k = 0; k < 128; ++k)
            s += bf2f(b_in[l * D + k]) * bf2f(W[k * D + t]);
        bc[b * D + t] = f2bf(s);
    }
}

// ---------------- pre-transpose + swizzle 13 weight mats ----------------
__global__ __launch_bounds__(256) void k_prepw(
    const unsigned short* __restrict__ wbase, const unsigned short* __restrict__ wc,
    unsigned short* __restrict__ wtg, int o4, int o7)
{
    int m = blockIdx.x >> 3;
    int sub = blockIdx.x & 7;
    const unsigned short* src;
    if (m == 0)       src = wbase;                         // w_proj
    else if (m <= 2)  src = wbase + o4 + (m - 1) * DD;     // w_in[l]
    else if (m <= 10) src = wc + (size_t)(m - 3) * DD;     // composed wc[l*4+r]
    else              src = wbase + o7 + (m - 11) * DD;    // w_out[l]
    int c = sub * 256 + threadIdx.x;   // 0..2047
    int n = c >> 4;
    int kc = c & 15;
    unsigned short tmp[8];
    #pragma unroll
    for (int ko = 0; ko < 8; ++ko) tmp[ko] = src[(kc * 8 + ko) * 128 + n];
    *((uint4*)(wtg + (size_t)m * DD + n * 128 + ((kc ^ (n & 15)) * 8))) = *(uint4*)tmp;
}

// ---------------- FAST gemm core: W pre-transposed/swizzled, A direct from global ----------------
__device__ __forceinline__ void load_afrag(
    const unsigned short* __restrict__ A, int M, int blockRow, short8 (&af)[2][4])
{
    int t = threadIdx.x;
    int wave = t >> 6, lane = t & 63, quad = lane >> 4, l16 = lane & 15;
    int rowbase = blockRow + wave * 32;
    int r0 = min(rowbase + l16, M - 1);
    int r1 = min(rowbase + 16 + l16, M - 1);
    const unsigned short* a0 = A + (size_t)r0 * D;
    const unsigned short* a1 = A + (size_t)r1 * D;
    #pragma unroll
    for (int ks = 0; ks < 4; ++ks) {
        int chunk = ks * 4 + quad;
        af[0][ks] = *((const short8*)(a0 + chunk * 8));
        af[1][ks] = *((const short8*)(a1 + chunk * 8));
    }
}

__device__ __forceinline__ void mfma_slice(
    const unsigned short* Wt, short8 (&af)[2][4], f32x4 (&acc)[2][8])
{
    int lane = threadIdx.x & 63, quad = lane >> 4, l16 = lane & 15;
    #pragma unroll
    for (int a = 0; a < 2; ++a)
        #pragma unroll
        for (int b = 0; b < 8; ++b) acc[a][b] = (f32x4){0.f, 0.f, 0.f, 0.f};
    #pragma unroll
    for (int ks = 0; ks < 4; ++ks) {
        int chunk = ks * 4 + quad;
        short8 bf[8];
        #pragma unroll
        for (int ct = 0; ct < 8; ++ct)
            bf[ct] = *((const short8*)&Wt[(ct * 16 + l16) * 128 + ((chunk ^ l16) * 8)]);
        #pragma unroll
        for (int rt = 0; rt < 2; ++rt)
            #pragma unroll
            for (int ct = 0; ct < 8; ++ct)
                acc[rt][ct] = __builtin_amdgcn_mfma_f32_16x16x32_bf16(af[rt][ks], bf[ct], acc[rt][ct], 0, 0, 0);
    }
}

__device__ __forceinline__ void gemm_core_fast(
    const unsigned short* __restrict__ A,
    const unsigned short* __restrict__ Wt_g,
    int M, int blockRow, unsigned short* Wt, f32x4 (&acc)[2][8])
{
    int t = threadIdx.x;
    #pragma unroll
    for (int i = 0; i < 8; ++i)
        ((uint4*)Wt)[t + i * 256] = ((const uint4*)Wt_g)[t + i * 256];
    short8 af[2][4];
    load_afrag(A, M, blockRow, af);
    #pragma unroll
    for (int a = 0; a < 2; ++a)
        #pragma unroll
        for (int b = 0; b < 8; ++b) acc[a][b] = (f32x4){0.f, 0.f, 0.f, 0.f};
    __syncthreads();
    mfma_slice(Wt, af, acc);
}

// ---------------- plain fast GEMM ----------------
__global__ __launch_bounds__(256) void gemm_fast(
    const unsigned short* __restrict__ A, const unsigned short* __restrict__ Wt_g,
    const unsigned short* __restrict__ bias, unsigned short* __restrict__ C,
    int M, int ldc, int coloff)
{
    __shared__ unsigned short Wt[DD];
    f32x4 acc[2][8];
    gemm_core_fast(A, Wt_g, M, blockIdx.x * 128, Wt, acc);
    store_c(acc, bias, C, M, blockIdx.x * 128, ldc, coloff);
}

// ---------------- proj GEMM + per-block BN partial stats ----------------
__global__ __launch_bounds__(256) void gemm_proj(
    const unsigned short* __restrict__ A, const unsigned short* __restrict__ Wt_g,
    const unsigned short* __restrict__ bias, unsigned short* __restrict__ C,
    int M, float* __restrict__ psum, float* __restrict__ psq)
{
    __shared__ unsigned short Wt[DD];
    __shared__ float smS[4][128], smQ[4][128];
    f32x4 acc[2][8];
    int blockRow = blockIdx.x * 128;
    gemm_core_fast(A, Wt_g, M, blockRow, Wt, acc);

    int t = threadIdx.x;
    int wave = t >> 6, lane = t & 63, quad = lane >> 4, l16 = lane & 15;
    int rowbase = wave * 32;
    #pragma unroll
    for (int ct = 0; ct < 8; ++ct) {
        int col = ct * 16 + l16;
        float bv = bf2f(bias[col]);
        float ps = 0.f, pq = 0.f;
        #pragma unroll
        for (int rt = 0; rt < 2; ++rt) {
            #pragma unroll
            for (int r = 0; r < 4; ++r) {
                int grow = blockRow + rowbase + rt * 16 + quad * 4 + r;
                if (grow < M) {
                    float v = acc[rt][ct][r] + bv;
                    C[(size_t)grow * D + col] = f2bf(v);
                    ps += v; pq += v * v;
                }
            }
        }
        ps += __shfl_xor(ps, 16, 64); ps += __shfl_xor(ps, 32, 64);
        pq += __shfl_xor(pq, 16, 64); pq += __shfl_xor(pq, 32, 64);
        if (quad == 0) { smS[wave][col] = ps; smQ[wave][col] = pq; }
    }
    __syncthreads();
    if (t < 128) {
        float s = smS[0][t] + smS[1][t] + smS[2][t] + smS[3][t];
        float q = smQ[0][t] + smQ[1][t] + smQ[2][t] + smQ[3][t];
        psum[blockIdx.x * 128 + t] = s;
        psq[blockIdx.x * 128 + t] = q;
    }
}

// ---------------- fused per-layer GEMM: slice 0 -> xl bf16 (dinv-scaled); 1..4 -> y fp8 slab ----------------
__global__ __launch_bounds__(256) void gemm_fused(
    const unsigned short* __restrict__ h, const unsigned short* __restrict__ wtg,
    const unsigned short* __restrict__ b_in_l, const unsigned short* __restrict__ bc_l,
    unsigned short* __restrict__ xl, unsigned char* __restrict__ y8,
    const float* __restrict__ dinv, int M, int Ntot, int l)
{
    __shared__ unsigned short Wt[DD];
    f32x4 acc[2][8];
    int slice = blockIdx.y;
    int m = (slice == 0) ? (1 + l) : (3 + l * 4 + slice - 1);
    int blockRow = blockIdx.x * 128;
    gemm_core_fast(h, wtg + (size_t)m * DD, M, blockRow, Wt, acc);
    int t = threadIdx.x;
    int wave = t >> 6, lane = t & 63, quad = lane >> 4, l16 = lane & 15;
    int rowbase = wave * 32;
    if (slice == 0) {
        #pragma unroll
        for (int rt = 0; rt < 2; ++rt) {
            float dv[4];
            #pragma unroll
            for (int r = 0; r < 4; ++r) {
                int grow = min(blockRow + rowbase + rt * 16 + quad * 4 + r, M - 1);
                dv[r] = dinv[grow];
            }
            #pragma unroll
            for (int ct = 0; ct < 8; ++ct) {
                int col = ct * 16 + l16;
                float bv = bf2f(b_in_l[col]);
                #pragma unroll
                for (int r = 0; r < 4; ++r) {
                    int grow = blockRow + rowbase + rt * 16 + quad * 4 + r;
                    if (grow < M)
                        xl[(size_t)grow * D + col] = f2bf((acc[rt][ct][r] + bv) * dv[r]);
                }
            }
        }
    } else {
        unsigned char* yd = y8 + (size_t)(slice - 1) * (size_t)Ntot * D;
        const unsigned short* bias = bc_l + (slice - 1) * D;
        #pragma unroll
        for (int rt = 0; rt < 2; ++rt) {
            #pragma unroll
            for (int ct = 0; ct < 8; ++ct) {
                int col = ct * 16 + l16;
                float bv = bf2f(bias[col]);
                #pragma unroll
                for (int r = 0; r < 4; ++r) {
                    int grow = blockRow + rowbase + rt * 16 + quad * 4 + r;
                    if (grow < M) {
                        float v = acc[rt][ct][r] + bv;
                        int p = __builtin_amdgcn_cvt_pk_fp8_f32(v, v, 0, false);
                        yd[(size_t)grow * D + col] = (unsigned char)(p & 0xFF);
                    }
                }
            }
        }
    }
}

// ---------------- final GEMM on compact zg rows + exact GeLU epilogue ----------------
__global__ __launch_bounds__(256) void gemm_out(
    const unsigned short* __restrict__ zg, const unsigned short* __restrict__ Wt_g,
    const unsigned short* __restrict__ bias, void* __restrict__ out,
    int M, const unsigned short* __restrict__ xprobe)
{
    int fl = vote_flag(xprobe);
    __shared__ unsigned short Wt[DD];
    f32x4 acc[2][8];
    int blockRow = blockIdx.x * 128;
    gemm_core_fast(zg, Wt_g, M, blockRow, Wt, acc);
    int t = threadIdx.x;
    int wave = t >> 6, lane = t & 63, quad = lane >> 4, l16 = lane & 15;
    int rowbase = wave * 32;
    #pragma unroll
    for (int rt = 0; rt < 2; ++rt) {
        #pragma unroll
        for (int ct = 0; ct < 8; ++ct) {
            int col = ct * 16 + l16;
            float bv = bf2f(bias[col]);
            #pragma unroll
            for (int r = 0; r < 4; ++r) {
                int grow = blockRow + rowbase + rt * 16 + quad * 4 + r;
                if (grow < M) {
                    float v = acc[rt][ct][r] + bv;
                    float gl = 0.5f * v * (1.f + erff(v * 0.70710678118654752f));
                    size_t o = (size_t)grow * D + col;
                    if (fl) ((float*)out)[o] = gl;
                    else    ((unsigned short*)out)[o] = f2bf(gl);
                }
            }
        }
    }
}

// ================= atomic-free CSR build via single-digit bucket sort =================
__global__ __launch_bounds__(256) void k_hista(
    const int* __restrict__ ei, int E,
    unsigned int* __restrict__ part_dst, unsigned int* __restrict__ part_src)
{
    __shared__ unsigned int hd[256], hs[256];
    int b = blockIdx.x, t = threadIdx.x;
    hd[t] = 0u; hs[t] = 0u;
    __syncthreads();
    int base = b * 2048;
    #pragma unroll
    for (int i = 0; i < 8; ++i) {
        int e = base + t + i * 256;
        if (e < E) {
            atomicAdd(&hd[((unsigned int)ei[e]) >> 8], 1u);
            atomicAdd(&hs[((unsigned int)ei[E + e]) >> 8], 1u);
        }
    }
    __syncthreads();
    part_dst[b * 256 + t] = hd[t];
    part_src[b * 256 + t] = hs[t];
}

__global__ void k_scanpart(unsigned int* __restrict__ part_d, unsigned int* __restrict__ part_s,
                           unsigned int* __restrict__ btot_d, unsigned int* __restrict__ btot_s,
                           int BA)
{
    __shared__ unsigned int arr[512];
    unsigned int* part = blockIdx.y ? part_s : part_d;
    unsigned int* btot = blockIdx.y ? btot_s : btot_d;
    int bucket = blockIdx.x, t = threadIdx.x;
    unsigned int v0 = (t < BA) ? part[t * 256 + bucket] : 0u;
    unsigned int v1 = (t + 256 < BA) ? part[(t + 256) * 256 + bucket] : 0u;
    arr[t] = v0; arr[t + 256] = v1;
    __syncthreads();
    for (int off = 1; off < 512; off <<= 1) {
        unsigned int a = arr[t], b2 = arr[t + 256];
        unsigned int pa = (t >= off) ? arr[t - off] : 0u;
        unsigned int pb = (t + 256 >= off) ? arr[t + 256 - off] : 0u;
        __syncthreads();
        arr[t] = a + pa; arr[t + 256] = b2 + pb;
        __syncthreads();
    }
    if (t < BA) part[t * 256 + bucket] = arr[t] - v0;
    if (t + 256 < BA) part[(t + 256) * 256 + bucket] = arr[t + 256] - v1;
    if (t == 0) btot[bucket] = arr[511];
}

__global__ void k_scanbase(const unsigned int* __restrict__ btot_d, const unsigned int* __restrict__ btot_s,
                           unsigned int* __restrict__ bbase_d, unsigned int* __restrict__ bbase_s)
{
    __shared__ unsigned int a1[256], a2[256];
    int t = threadIdx.x;
    unsigned int vd = btot_d[t], vs = btot_s[t];
    a1[t] = vd; a2[t] = vs;
    __syncthreads();
    for (int off = 1; off < 256; off <<= 1) {
        unsigned int x = a1[t], y = a2[t];
        unsigned int px = (t >= off) ? a1[t - off] : 0u;
        unsigned int py = (t >= off) ? a2[t - off] : 0u;
        __syncthreads();
        a1[t] = x + px; a2[t] = y + py;
        __syncthreads();
    }
    bbase_d[t] = a1[t] - vd;
    bbase_s[t] = a2[t] - vs;
    if (t == 255) { bbase_d[256] = a1[255]; bbase_s[256] = a2[255]; }
}

__global__ __launch_bounds__(256) void k_bscatter(
    const int* __restrict__ ei, const int* __restrict__ et, int E,
    const unsigned int* __restrict__ part_dst, const unsigned int* __restrict__ part_src,
    const unsigned int* __restrict__ bbase_d, const unsigned int* __restrict__ bbase_s,
    uint2* __restrict__ ebuck, unsigned short* __restrict__ sbuck)
{
    __shared__ unsigned int cd[256], cs[256];
    int b = blockIdx.x, t = threadIdx.x;
    cd[t] = part_dst[b * 256 + t] + bbase_d[t];
    cs[t] = part_src[b * 256 + t] + bbase_s[t];
    __syncthreads();
    int base = b * 2048;
    #pragma unroll
    for (int i = 0; i < 8; ++i) {
        int e = base + t + i * 256;
        if (e < E) {
            unsigned int d = (unsigned int)ei[e];
            unsigned int s = (unsigned int)ei[E + e];
            unsigned int tt = (unsigned int)et[e];
            unsigned int pd = atomicAdd(&cd[d >> 8], 1u);
            ebuck[pd] = make_uint2(d, s | (tt << 16));
            unsigned int ps = atomicAdd(&cs[s >> 8], 1u);
            sbuck[ps] = (unsigned short)s;
        }
    }
}

// y=0: per-dst-bucket counting sort on key (dloc<<2|type) -> rp + type-subsorted pckd
// y=1: per-src-bucket histogram -> dinv
__global__ __launch_bounds__(256) void k_buckets(
    const unsigned int* __restrict__ bbase_d, const uint2* __restrict__ ebuck,
    unsigned int* __restrict__ rp, unsigned int* __restrict__ pckd,
    const unsigned int* __restrict__ bbase_s, const unsigned short* __restrict__ sbuck,
    float* __restrict__ dinv, int N)
{
    __shared__ uint2 ebuf[BCAP];
    __shared__ unsigned int bins[1024], gsum[256];
    int b = blockIdx.x, t = threadIdx.x;
    if (blockIdx.y == 0) {
        unsigned int beg = bbase_d[b], end = bbase_d[b + 1];
        unsigned int cnt = end - beg;
        #pragma unroll
        for (int j = 0; j < 4; ++j) bins[t + j * 256] = 0u;
        __syncthreads();
        bool fit = cnt <= (unsigned int)BCAP;
        if (fit) {
            for (unsigned int i = t; i < cnt; i += 256) {
                uint2 v = ebuck[beg + i];
                ebuf[i] = v;
                atomicAdd(&bins[((v.x & 255u) << 2) | ((v.y >> 16) & 3u)], 1u);
            }
        } else {
            for (unsigned int i = t; i < cnt; i += 256) {
                uint2 v = ebuck[beg + i];
                atomicAdd(&bins[((v.x & 255u) << 2) | ((v.y >> 16) & 3u)], 1u);
            }
        }
        __syncthreads();
        unsigned int b0 = bins[4 * t], b1 = bins[4 * t + 1], b2 = bins[4 * t + 2], b3 = bins[4 * t + 3];
        unsigned int s4 = b0 + b1 + b2 + b3;
        gsum[t] = s4;
        __syncthreads();
        for (int off = 1; off < 256; off <<= 1) {
            unsigned int v = gsum[t];
            unsigned int a = (t >= off) ? gsum[t - off] : 0u;
            __syncthreads();
            gsum[t] = v + a;
            __syncthreads();
        }
        unsigned int base0 = gsum[t] - s4;
        bins[4 * t]     = base0;
        bins[4 * t + 1] = base0 + b0;
        bins[4 * t + 2] = base0 + b0 + b1;
        bins[4 * t + 3] = base0 + b0 + b1 + b2;
        int n = (b << 8) + t;
        if (n <= N) rp[n] = beg + base0;
        __syncthreads();
        if (fit) {
            for (unsigned int i = t; i < cnt; i += 256) {
                uint2 v = ebuf[i];
                unsigned int key = ((v.x & 255u) << 2) | ((v.y >> 16) & 3u);
                unsigned int pos = beg + atomicAdd(&bins[key], 1u);
                pckd[pos] = v.y;
            }
        } else {
            for (unsigned int i = t; i < cnt; i += 256) {
                uint2 v = ebuck[beg + i];
                unsigned int key = ((v.x & 255u) << 2) | ((v.y >> 16) & 3u);
                unsigned int pos = beg + atomicAdd(&bins[key], 1u);
                pckd[pos] = v.y;
            }
        }
    } else {
        unsigned int beg = bbase_s[b], end = bbase_s[b + 1];
        bins[t] = 0u;
        __syncthreads();
        for (unsigned int i = beg + t; i < end; i += 256)
            atomicAdd(&bins[sbuck[i] & 255u], 1u);
        __syncthreads();
        int n = (b << 8) + t;
        if (n < N) {
            unsigned int dg = bins[t];
            dinv[n] = dg ? rsqrtf((float)dg) : 0.f;
        }
    }
}

// ---------------- BN stats reduce (1 block) ----------------
__global__ void k_bnstats(const float* __restrict__ psum, const float* __restrict__ psq,
                          int nb, int N, const unsigned short* __restrict__ g,
                          const unsigned short* __restrict__ b,
                          float* __restrict__ scale, float* __restrict__ shift) {
    int col = threadIdx.x & 127, h = threadIdx.x >> 7;
    float s = 0.f, q = 0.f;
    for (int i = h; i < nb; i += 2) { s += psum[i * 128 + col]; q += psq[i * 128 + col]; }
    __shared__ float sS[256], sQ[256];
    sS[threadIdx.x] = s; sQ[threadIdx.x] = q;
    __syncthreads();
    if (h == 0) {
        s = sS[col] + sS[col + 128];
        q = sQ[col] + sQ[col + 128];
        float inv = 1.f / (float)N;
        float mean = s * inv;
        float var = fmaxf(q * inv - mean * mean, 0.f);
        float sc = rsqrtf(var + 1e-5f) * bf2f(g[col]);
        scale[col] = sc;
        shift[col] = bf2f(b[col]) - mean * sc;
    }
}

// ---------------- BN apply + relu (vec 8 shorts/thread) ----------------
__global__ void k_bnrelu(unsigned short* __restrict__ h, const float* __restrict__ scale,
                         const float* __restrict__ shift, int n8) {
    int i = blockIdx.x * blockDim.x + threadIdx.x;
    if (i >= n8) return;
    int cb = (i & 15) * 8;
    uint4 v = ((uint4*)h)[i];
    unsigned int* w = (unsigned int*)&v;
    #pragma unroll
    for (int j = 0; j < 4; ++j) {
        int c = cb + j * 2;
        float v0 = __uint_as_float(w[j] << 16);
        float v1 = __uint_as_float(w[j] & 0xFFFF0000u);
        v0 = fmaxf(fmaf(v0, scale[c], shift[c]), 0.f);
        v1 = fmaxf(fmaf(v1, scale[c + 1], shift[c + 1]), 0.f);
        w[j] = (unsigned int)f2bf(v0) | ((unsigned int)f2bf(v1) << 16);
    }
    ((uint4*)h)[i] = v;
}

// ---------------- edge aggregation: 1 wave/node, 8 edges in flight, fp8 y stream ----------------
__device__ __forceinline__ void acc_edge8(uint4 xv, uint2 yv, float vm,
                                          float* g, float* dd, float* ss) {
    const unsigned int* xw = (const unsigned int*)&xv;
    const unsigned int* yw = (const unsigned int*)&yv;
    #pragma unroll
    for (int w = 0; w < 2; ++w) {
        auto ylo = __builtin_amdgcn_cvt_pk_f32_fp8(yw[w], false);  // bytes 0,1
        auto yhi = __builtin_amdgcn_cvt_pk_f32_fp8(yw[w], true);   // bytes 2,3
        float vy0 = ylo[0], vy1 = ylo[1], vy2 = yhi[0], vy3 = yhi[1];
        unsigned int xa = xw[2 * w], xb2 = xw[2 * w + 1];
        float x0 = __uint_as_float(xa << 16);
        float x1 = __uint_as_float(xa & 0xFFFF0000u);
        float x2 = __uint_as_float(xb2 << 16);
        float x3 = __uint_as_float(xb2 & 0xFFFF0000u);
        int j = 4 * w;
        g[j + 0] = fmaf(x0, vm, g[j + 0]);
        g[j + 1] = fmaf(x1, vm, g[j + 1]);
        g[j + 2] = fmaf(x2, vm, g[j + 2]);
        g[j + 3] = fmaf(x3, vm, g[j + 3]);
        float e0 = __expf(vy0), e1 = __expf(vy1), e2 = __expf(vy2), e3 = __expf(vy3);
        dd[j + 0] = fmaf(e0, vm, dd[j + 0]); ss[j + 0] = fmaf(vy0 * e0, vm, ss[j + 0]);
        dd[j + 1] = fmaf(e1, vm, dd[j + 1]); ss[j + 1] = fmaf(vy1 * e1, vm, ss[j + 1]);
        dd[j + 2] = fmaf(e2, vm, dd[j + 2]); ss[j + 2] = fmaf(vy2 * e2, vm, ss[j + 2]);
        dd[j + 3] = fmaf(e3, vm, dd[j + 3]); ss[j + 3] = fmaf(vy3 * e3, vm, ss[j + 3]);
    }
}

__global__ __launch_bounds__(256) void k_edge(
    const unsigned int* __restrict__ rp, const unsigned int* __restrict__ packed,
    const unsigned short* __restrict__ xl, const unsigned char* __restrict__ y8,
    const float* __restrict__ dinv, unsigned short* __restrict__ zout,
    int NN, int Ntot, const int* __restrict__ nodes)
{
    int lane = threadIdx.x & 63;
    int slot = blockIdx.x * 4 + (threadIdx.x >> 6);
    if (slot >= NN) return;
    int node = nodes ? nodes[slot] : slot;
    node = __builtin_amdgcn_readfirstlane(node);
    unsigned int beg = rp[node], end = rp[node + 1];
    int eg = lane >> 4;
    int cb = (lane & 15) * 8;
    float g[8], dd[8], ss[8];
    #pragma unroll
    for (int j = 0; j < 8; ++j) { g[j] = 0.f; dd[j] = 0.f; ss[j] = 0.f; }

    for (unsigned int e0 = beg; e0 < end; e0 += 8) {
        unsigned int eA = e0 + (unsigned int)eg;
        unsigned int eB = eA + 4u;
        float vmA = (eA < end) ? 1.f : 0.f;
        float vmB = (eB < end) ? 1.f : 0.f;
        unsigned int pA = packed[(eA < end) ? eA : beg];
        unsigned int pB = packed[(eB < end) ? eB : beg];
        unsigned int sA = pA & 0xFFFFu, tA = (pA >> 16) & 3u;
        unsigned int sB = pB & 0xFFFFu, tB = (pB >> 16) & 3u;
        uint4 xvA = *((const uint4*)(xl + (size_t)sA * D + cb));
        uint2 yvA = *((const uint2*)(y8 + ((size_t)tA * Ntot + sA) * D + cb));
        uint4 xvB = *((const uint4*)(xl + (size_t)sB * D + cb));
        uint2 yvB = *((const uint2*)(y8 + ((size_t)tB * Ntot + sB) * D + cb));
        acc_edge8(xvA, yvA, vmA, g, dd, ss);
        acc_edge8(xvB, yvB, vmB, g, dd, ss);
    }

    #pragma unroll
    for (int j = 0; j < 8; ++j) {
        g[j]  += __shfl_xor(g[j], 16, 64);  g[j]  += __shfl_xor(g[j], 32, 64);
        dd[j] += __shfl_xor(dd[j], 16, 64); dd[j] += __shfl_xor(dd[j], 32, 64);
        ss[j] += __shfl_xor(ss[j], 16, 64); ss[j] += __shfl_xor(ss[j], 32, 64);
    }
    if (eg == 0) {
        float dn = dinv[node];
        unsigned int o[4];
        #pragma unroll
        for (int w = 0; w < 4; ++w) {
            int j0 = w * 2, j1 = w * 2 + 1;
            float m0 = (dd[j0] > 0.f) ? ss[j0] / dd[j0] : 0.f;
            float m1 = (dd[j1] > 0.f) ? ss[j1] / dd[j1] : 0.f;
            float z0 = fmaf(g[j0], dn, 0.1f * fmaxf(m0, 0.f));
            float z1 = fmaf(g[j1], dn, 0.1f * fmaxf(m1, 0.f));
            o[w] = (unsigned int)f2bf(z0) | ((unsigned int)f2bf(z1) << 16);
        }
        *((uint4*)(zout + (size_t)slot * D + cb)) = *(uint4*)o;
    }
}

extern "C" void kernel_launch(void* const* d_in, const int* in_sizes, int n_in,
                              void* d_out, int out_size, void* d_ws, size_t ws_size,
                              hipStream_t stream)
{
    const int* ei  = (const int*)d_in[1];
    const int* idx = (const int*)d_in[2];
    const int* et  = (const int*)d_in[3];
    const unsigned short* xprobe = (const unsigned short*)d_in[0];

    int N  = in_sizes[0] / D;            // 48758
    int E  = in_sizes[1] / 2;            // 780000
    int NI = in_sizes[2];                // 10000
    int L  = in_sizes[9] / (D * D);      // 2
    int R  = in_sizes[11] / (L * D * D); // 4

    int NB = (N + 255) >> 8;             // dst/src buckets
    int BA = (E + 2047) / 2048;          // histogram/scatter blocks

    char* ws = (char*)d_ws;
    size_t off = 0;
    auto alloc = [&](size_t bytes) -> char* {
        char* p = ws + off;
        off += (bytes + 255) & ~(size_t)255;
        return p;
    };
    unsigned short* h    = (unsigned short*)alloc((size_t)N * D * 2);
    unsigned short* xl   = (unsigned short*)alloc((size_t)N * D * 2);
    unsigned char*  y8   = (unsigned char*)alloc((size_t)N * R * D);   // fp8 [type][node][D]
    unsigned short* z    = (unsigned short*)alloc((size_t)N * D * 2);
    unsigned short* xb   = (unsigned short*)alloc((size_t)N * D * 2);
    unsigned short* zg   = (unsigned short*)alloc((size_t)NI * D * 2);
    float*          dinv = (float*)alloc((size_t)N * 4);
    unsigned int*   rp   = (unsigned int*)alloc((size_t)(N + 1) * 4);
    unsigned int*   pckd = (unsigned int*)alloc((size_t)E * 4);
    int gb  = (N + 127) / 128;
    float*          psum = (float*)alloc((size_t)gb * 128 * 4);
    float*          psq  = (float*)alloc((size_t)gb * 128 * 4);
    float*          bscale = (float*)alloc(128 * 4);
    float*          bshift = (float*)alloc(128 * 4);
    // bucket-sort scratch
    unsigned int*   part_dst = (unsigned int*)alloc((size_t)BA * 256 * 4);
    unsigned int*   part_src = (unsigned int*)alloc((size_t)BA * 256 * 4);
    unsigned int*   btot_d   = (unsigned int*)alloc(256 * 4);
    unsigned int*   btot_s   = (unsigned int*)alloc(256 * 4);
    unsigned int*   bbase_d  = (unsigned int*)alloc(257 * 4);
    unsigned int*   bbase_s  = (unsigned int*)alloc(257 * 4);
    // aliases into regions dead during graph prep (E*8 = 6.24 MB <= N*R*D = 25 MB; E*2 <= N*D*2)
    uint2*          ebuck = (uint2*)y8;
    unsigned short* sbuck = (unsigned short*)z;
    // contiguous bf16 weight region
    int o1 = D * D;                // w_proj
    int o2 = o1 + D;               // b_proj
    int o3 = o2 + D;               // bn_g
    int o4 = o3 + D;               // bn_b
    int o5 = o4 + L * D * D;       // w_in
    int o6 = o5 + L * D;           // b_in
    int o7 = o6 + L * R * D * D;   // w_rel
    int o8 = o7 + L * D * D;       // w_out
    int wt = o8 + L * D;           // b_out end
    unsigned short* wbase  = (unsigned short*)alloc((size_t)wt * 2);
    unsigned short* b_proj = wbase + o1;
    unsigned short* g_bn   = wbase + o2;
    unsigned short* b_bn   = wbase + o3;
    unsigned short* w_in   = wbase + o4;
    unsigned short* b_in   = wbase + o5;
    unsigned short* w_rel  = wbase + o6;
    unsigned short* b_out  = wbase + o8;
    unsigned short* wc     = (unsigned short*)alloc((size_t)L * R * D * D * 2);
    unsigned short* bc     = (unsigned short*)alloc((size_t)L * R * D * 2);
    unsigned short* wtg    = (unsigned short*)alloc((size_t)13 * DD * 2);
    (void)ws_size; (void)n_in; (void)out_size;

    int gb2 = (NI + 127) / 128;
    int nb4 = (N + 3) / 4;
    int ni4 = (NI + 3) / 4;

    // input normalization (dtype vote inline)
    int n4 = N * D / 4;
    int nbx = (n4 + 255) / 256;
    int nbw = (wt + 255) / 256;
    k_normall<<<nbx + nbw, 256, 0, stream>>>(
        d_in[0], xb, n4, nbx,
        d_in[5], d_in[6], d_in[7], d_in[8], d_in[9], d_in[10], d_in[11], d_in[12], d_in[13],
        o1, o2, o3, o4, o5, o6, o7, o8, wt, wbase);

    // atomic-free CSR build (type-subsorted per dst)
    k_hista<<<BA, 256, 0, stream>>>(ei, E, part_dst, part_src);
    k_scanpart<<<dim3(256, 2), 256, 0, stream>>>(part_dst, part_src, btot_d, btot_s, BA);
    k_scanbase<<<1, 256, 0, stream>>>(btot_d, btot_s, bbase_d, bbase_s);
    k_bscatter<<<BA, 256, 0, stream>>>(ei, et, E, part_dst, part_src, bbase_d, bbase_s, ebuck, sbuck);
    k_buckets<<<dim3(NB, 2), 256, 0, stream>>>(bbase_d, ebuck, rp, pckd, bbase_s, sbuck, dinv, N);

    // composed weights, then pre-transposed/swizzled GEMM weights
    gemm_compose<<<L * R, 256, 0, stream>>>(w_in, w_rel, b_in, wc, bc);
    k_prepw<<<13 * 8, 256, 0, stream>>>(wbase, wc, wtg, o4, o7);

    // proj + BN + relu
    gemm_proj<<<gb, 256, 0, stream>>>(xb, wtg, b_proj, h, N, psum, psq);
    k_bnstats<<<1, 256, 0, stream>>>(psum, psq, gb, N, g_bn, b_bn, bscale, bshift);
    int n8 = N * D / 8;
    k_bnrelu<<<(n8 + 255) / 256, 256, 0, stream>>>(h, bscale, bshift, n8);

    // layer 0 (full graph)
    gemm_fused<<<dim3(gb, 1 + R), 256, 0, stream>>>(h, wtg, b_in, bc, xl, y8, dinv, N, N, 0);
    k_edge<<<nb4, 256, 0, stream>>>(rp, pckd, xl, y8, dinv, z, N, N, nullptr);
    gemm_fast<<<gb, 256, 0, stream>>>(z, wtg + (size_t)11 * DD, b_out, h, N, D, 0);

    // layer 1 (aggregate only idx rows, compact output)
    gemm_fused<<<dim3(gb, 1 + R), 256, 0, stream>>>(h, wtg, b_in + D, bc + R * D, xl, y8, dinv, N, N, 1);
    k_edge<<<ni4, 256, 0, stream>>>(rp, pckd, xl, y8, dinv, zg, NI, N, idx);

    // final GEMM on compact rows + GeLU
    gemm_out<<<gb2, 256, 0, stream>>>(zg, wtg + (size_t)12 * DD, b_out + D, d_out, NI, xprobe);
}